// Round 8
// baseline (1000.050 us; speedup 1.0000x reference)
//
#include <hip/hip_runtime.h>
#include <math.h>

typedef _Float16 half_t;
typedef __attribute__((ext_vector_type(8))) _Float16 f16x8;
typedef __attribute__((ext_vector_type(4))) _Float16 f16x4;
typedef __attribute__((ext_vector_type(4))) float f32x4;

#define MFMA16(a, b, c) __builtin_amdgcn_mfma_f32_16x16x32_f16((a), (b), (c), 0, 0, 0)

constexpr int Bc = 4, NQ = 2048, NKC = 2048, CC = 1024, NHD = 16, HDIM = 64;

__device__ __forceinline__ void async_copy16(half_t* lds, const half_t* g) {
  __builtin_amdgcn_global_load_lds(
      (const __attribute__((address_space(1))) unsigned*)g,
      (__attribute__((address_space(3))) unsigned*)lds, 16, 0, 0);
}

// ---------------------------------------------------------------------------
// fp32 -> fp16 weight converts (8 elems/thread, 4 weights batched)
// ---------------------------------------------------------------------------
__global__ __launch_bounds__(256) void cvtW(const float* __restrict__ s0,
                                            const float* __restrict__ s1,
                                            const float* __restrict__ s2,
                                            const float* __restrict__ s3,
                                            half_t* __restrict__ dst) {
  const int y = blockIdx.y;
  const float* src = (y == 0) ? s0 : (y == 1) ? s1 : (y == 2) ? s2 : s3;
  const int i = blockIdx.x * 256 + threadIdx.x;
  const f32x4 a = ((const f32x4*)src)[2 * i];
  const f32x4 b = ((const f32x4*)src)[2 * i + 1];
  f16x8 h;
#pragma unroll
  for (int j = 0; j < 4; ++j) { h[j] = (half_t)a[j]; h[4 + j] = (half_t)b[j]; }
  ((f16x8*)(dst + (size_t)y * CC * CC))[i] = h;
}

// ---------------------------------------------------------------------------
// GEMM (m97 structure): out[m][n] = sum_k X[m][k]*W[n][k], MFMA fp16.
// 128x128 tile, BK=32, unpadded LDS.
//   CVT:  X is fp32; A-operand reg-staged (f32x4 loads -> cvt -> ds_write_b128,
//         prefetched across the MFMA phase). Replaces the standalone cvt16.
//   ROPE: RoPE2D fused into the fp16 epilogue (exact fp16 emulation of the
//         standalone rope kernel: pair (i, i+16) lives in the same thread at
//         ni even/odd with i = l16). Replaces the standalone rope kernel.
//   FINAL: fp16 X via global_load_lds, fp32 out + bias.
// launch_bounds(256,2): grid is 512 blocks = exactly 2 blocks/CU, so cap the
// occupancy target at 2 waves/EU -> 256-VGPR budget. Round 6's default bounds
// made the allocator pick 64 VGPRs and spill the CVT loop state to scratch
// (WRITE_SIZE 966 MB, 346 us). Est. live set ~120 VGPR + 64 AGPR acc.
// ---------------------------------------------------------------------------
template <bool CVT, bool ROPE, bool FINAL>
__global__ __launch_bounds__(256, 2) void gemm_k(const void* __restrict__ Xv,
                                                 const half_t* __restrict__ W,
                                                 half_t* __restrict__ out16,
                                                 float* __restrict__ outf,
                                                 const float* __restrict__ bias,
                                                 const int* __restrict__ pos) {
  __shared__ half_t As[128 * 32];
  __shared__ half_t Bs[128 * 32];
  const int tid  = threadIdx.x;
  const int wave = tid >> 6, lane = tid & 63;
  const int quad = lane >> 4, l16 = lane & 15;
  const int m0 = blockIdx.y * 128, n0 = blockIdx.x * 128;
  const int mw = (wave >> 1) * 64, nw = (wave & 1) * 64;

  // B staging via global_load_lds (weights, fp16): instr i covers rows
  // wave*32+i*16..+16; lane: row += lane/4, k = (lane&3)*8.
  const int srow = lane >> 2, skoff = (lane & 3) * 8;
  const half_t* xb = W + (size_t)(n0 + wave * 32 + srow) * CC + skoff;
  half_t* lB0 = &Bs[(wave * 2 + 0) * 512];
  half_t* lB1 = &Bs[(wave * 2 + 1) * 512];

  // A staging (fp16 path): same gll pattern as B.
  const half_t* xa = CVT ? nullptr : (const half_t*)Xv + (size_t)(m0 + wave * 32 + srow) * CC + skoff;
  half_t* lA0 = &As[(wave * 2 + 0) * 512];
  half_t* lA1 = &As[(wave * 2 + 1) * 512];

  // A staging (fp32 CVT path): thread covers row = tid/2, halfs [akh, akh+16).
  const int arow = tid >> 1, akh = (tid & 1) * 16;
  const float* xsrc = CVT ? (const float*)Xv + (size_t)(m0 + arow) * CC + akh : nullptr;
  half_t* adst = &As[arow * 32 + akh];

  f32x4 acc[4][4] = {};
  f32x4 ar[4];
  if constexpr (CVT) {
#pragma unroll
    for (int j = 0; j < 4; ++j) ar[j] = ((const f32x4*)xsrc)[j];  // k0 = 0
  }

  for (int k0 = 0; k0 < CC; k0 += 32) {
    __syncthreads();
    if constexpr (CVT) {
      f16x8 h0, h1;
#pragma unroll
      for (int j = 0; j < 4; ++j) {
        h0[j] = (half_t)ar[0][j]; h0[4 + j] = (half_t)ar[1][j];
        h1[j] = (half_t)ar[2][j]; h1[4 + j] = (half_t)ar[3][j];
      }
      *(f16x8*)adst = h0;
      *(f16x8*)(adst + 8) = h1;
    } else {
      async_copy16(lA0, xa + k0);
      async_copy16(lA1, xa + 16 * CC + k0);
    }
    async_copy16(lB0, xb + k0);
    async_copy16(lB1, xb + 16 * CC + k0);
    __syncthreads();

    if constexpr (CVT) {
      if (k0 + 32 < CC) {
        const float* xn = xsrc + k0 + 32;
#pragma unroll
        for (int j = 0; j < 4; ++j) ar[j] = ((const f32x4*)xn)[j];
      }
    }

    f16x8 af[4], bf[4];
#pragma unroll
    for (int mi = 0; mi < 4; ++mi) af[mi] = *(const f16x8*)&As[(mw + mi * 16 + l16) * 32 + quad * 8];
#pragma unroll
    for (int ni = 0; ni < 4; ++ni) bf[ni] = *(const f16x8*)&Bs[(nw + ni * 16 + l16) * 32 + quad * 8];
#pragma unroll
    for (int mi = 0; mi < 4; ++mi)
#pragma unroll
      for (int ni = 0; ni < 4; ++ni) acc[mi][ni] = MFMA16(af[mi], bf[ni], acc[mi][ni]);
  }

  if constexpr (FINAL) {
#pragma unroll
    for (int mi = 0; mi < 4; ++mi)
#pragma unroll
      for (int ni = 0; ni < 4; ++ni)
#pragma unroll
        for (int r = 0; r < 4; ++r) {
          const size_t row = (size_t)(m0 + mw + mi * 16 + quad * 4 + r);
          const size_t col = (size_t)(n0 + nw + ni * 16 + l16);
          outf[row * CC + col] = acc[mi][ni][r] + bias[col];
        }
  } else if constexpr (ROPE) {
#pragma clang fp contract(off)
    // i = l16 (pair partner at col+16 is ni odd, same thread, same r)
    const float inv = __builtin_amdgcn_exp2f((float)l16 * -0.41524100904865773f);
#pragma unroll
    for (int mi = 0; mi < 4; ++mi)
#pragma unroll
      for (int np = 0; np < 2; ++np)
#pragma unroll
        for (int r = 0; r < 4; ++r) {
          const int row = m0 + mw + mi * 16 + quad * 4 + r;   // flattened b*NQ+n
          const int col1 = n0 + nw + np * 32 + l16;
          const int halfsel = (col1 >> 5) & 1;
          const int p = pos[(row << 1) + halfsel];
          const float ang = (float)p * inv;
          const half_t hc = (half_t)cosf(ang);
          const half_t hs = (half_t)sinf(ang);
          const half_t t1 = (half_t)acc[mi][2 * np + 0][r];
          const half_t t2 = (half_t)acc[mi][2 * np + 1][r];
          const half_t p1 = t1 * hc;
          const half_t p2 = t2 * hs;
          const half_t p3 = t2 * hc;
          const half_t p4 = t1 * hs;
          out16[(size_t)row * CC + col1]      = p1 - p2;
          out16[(size_t)row * CC + col1 + 16] = p3 + p4;
        }
  } else {
#pragma unroll
    for (int mi = 0; mi < 4; ++mi)
#pragma unroll
      for (int ni = 0; ni < 4; ++ni)
#pragma unroll
        for (int r = 0; r < 4; ++r) {
          const size_t row = (size_t)(m0 + mw + mi * 16 + quad * 4 + r);
          const size_t col = (size_t)(n0 + nw + ni * 16 + l16);
          out16[row * CC + col] = (half_t)acc[mi][ni][r];
        }
  }
}

// ---------------------------------------------------------------------------
// Flash attention, swapped-operand, batched-phase pipeline (round-5, 110 us).
//   K: double-buffered global_load_lds, fragment-ordered via per-lane source.
//   V: reg-staged transpose pack, single swizzled buffer.
//   QK phase: K-frag pair read once per kb (shared across mi), ALL 16 MFMAs
//   issued into live st[2][4] (max ILP), THEN batched exp+pack pass and
//   8 ds_write_b64 -> one Pb settle -> ALL PV MFMA (V frags shared across
//   mi) -> rendezvous-only "s_waitcnt lgkmcnt(0)" + s_barrier (next-tile
//   loads stay in flight across it).
// LDS = 16 (Kf dbuf) + 8 (Vfd) + 16 (Pb) = 40 KB -> 4 blocks/CU.
// ---------------------------------------------------------------------------
__global__ __launch_bounds__(256, 4) void attn_kernel(const half_t* __restrict__ q16,
                                                      const half_t* __restrict__ k16,
                                                      const half_t* __restrict__ v16,
                                                      half_t* __restrict__ x16) {
  // K fragments, double-buffered: [buf][kb][kc][slot=quad*16+l16][8 halfs] (16 KB)
  __shared__ __align__(16) half_t Kf[2 * 4096];
  // V^T fragments: [kc][nd][slot'][8 halfs], slot' = quad*16 + (l16 ^ quad ^ (kc<<2)) (8 KB)
  __shared__ __align__(16) unsigned Vfd[2 * 4 * 64 * 4];
  // P key-pair dwords: [wave][mi][q=l16][m ^ ((l16&7)<<2)], m = key/2 (16 KB)
  __shared__ __align__(16) unsigned Pb[4][2][16][32];

  const int tid  = threadIdx.x;
  const int wave = tid >> 6, lane = tid & 63;
  const int quad = lane >> 4, l16 = lane & 15;
  const int lx   = lane ^ quad;  // V-read slot base (quad XORed into low bits)
  const int psw  = (l16 & 7) << 2;
  const int qblk = blockIdx.x, h = blockIdx.y, b = blockIdx.z;
  const f32x4 zero = {0.f, 0.f, 0.f, 0.f};

  // Q fragments (B-operand role): rows wave*32 + mi*16 + l16, k = kc*32 + quad*8
  f16x8 qa[2][2];
  {
    const half_t* qbase =
        q16 + (size_t)(b * NQ + qblk * 128 + wave * 32 + l16) * CC + h * HDIM + quad * 8;
#pragma unroll
    for (int mi = 0; mi < 2; ++mi)
#pragma unroll
      for (int kc = 0; kc < 2; ++kc)
        qa[mi][kc] = *(const f16x8*)(qbase + (size_t)mi * 16 * CC + kc * 32);
  }

  f32x4 o[2][4] = {};   // O^T fragments: [mi][nd], rows d = nd*16+quad*4+r, col q = l16
  f32x4 lpv[2] = {};    // per-lane partial row sums, split by r (short add chains)

  // K gll: wave w stages kb=w. Per-lane global source so linear LDS dest
  // (base + lane*16) lands in fragment order: key = w*16 + l16, d = quad*8 + kc*32.
  const half_t* kga = k16 + (size_t)(b * NKC + wave * 16 + l16) * CC + h * HDIM + quad * 8;

  // V staging: thread covers keys {2vp, 2vp+1}, d = vd0..vd0+7
  const int vp = tid & 31, vd0 = (tid >> 5) * 8;
  const half_t* vptr = v16 + (size_t)(b * NKC + 2 * vp) * CC + h * HDIM + vd0;
  const int vkc = vp >> 4, vqd = (vp & 15) >> 2, vnd = vd0 >> 4;
  const int vl16b = vd0 & 15;  // 0 or 8
  const int vswz  = vqd ^ (vkc << 2);
  const int vbase = ((vkc * 4 + vnd) * 64 + vqd * 16) * 4 + (vp & 3);

  // prologue: tile 0 in flight
  async_copy16(&Kf[(wave * 2 + 0) * 512], kga);
  async_copy16(&Kf[(wave * 2 + 1) * 512], kga + 32);
  f16x8 vr0 = *(const f16x8*)vptr;
  f16x8 vr1 = *(const f16x8*)(vptr + CC);

  int cur = 0;
  for (int kt = 0; kt < NKC; kt += 64) {
    // V transpose-pack into Vfd (this tile); rendezvous barrier of prev iter
    // guarantees all waves' reads of Vfd are complete.
#pragma unroll
    for (int i = 0; i < 8; ++i) {
      union { half_t h2[2]; unsigned u; } pk;
      pk.h2[0] = vr0[i]; pk.h2[1] = vr1[i];
      Vfd[vbase + (((vl16b + i) ^ vswz) << 2)] = pk.u;
    }
    __syncthreads();  // full drain: Kf[cur] gll (issued a tile ago) landed; Vfd visible

    if (kt + 64 < NKC) {  // issue next K tile (other buffer) + next V reg loads
      const half_t* kn = kga + (size_t)(kt + 64) * CC;
      async_copy16(&Kf[(cur ^ 1) * 4096 + (wave * 2 + 0) * 512], kn);
      async_copy16(&Kf[(cur ^ 1) * 4096 + (wave * 2 + 1) * 512], kn + 32);
      const half_t* vn = vptr + (size_t)(kt + 64) * CC;
      vr0 = *(const f16x8*)vn;
      vr1 = *(const f16x8*)(vn + CC);
    }

    const half_t* Kc = &Kf[cur * 4096];

    // Phase 1a: S^T = K.Q^T, ALL 16 MFMAs live in st[2][4] (K-frags read once per kb)
    f32x4 st[2][4];
    __builtin_amdgcn_s_setprio(1);
#pragma unroll
    for (int kb = 0; kb < 4; ++kb) {
      const f16x8 ka0 = *(const f16x8*)&Kc[((kb * 2 + 0) * 64 + lane) * 8];
      const f16x8 ka1 = *(const f16x8*)&Kc[((kb * 2 + 1) * 64 + lane) * 8];
#pragma unroll
      for (int mi = 0; mi < 2; ++mi) {
        const f32x4 t0 = MFMA16(ka0, qa[mi][0], zero);
        st[mi][kb] = MFMA16(ka1, qa[mi][1], t0);
      }
    }
    __builtin_amdgcn_s_setprio(0);

    // Phase 1b: batched exp + in-lane pack + 8 ds_write_b64
#pragma unroll
    for (int mi = 0; mi < 2; ++mi)
#pragma unroll
      for (int kb = 0; kb < 4; ++kb) {
        f16x4 w;
#pragma unroll
        for (int r = 0; r < 4; ++r) {
          const float p = __builtin_amdgcn_exp2f(st[mi][kb][r] * 0.18033688011112042f);
          lpv[mi][r] += p;
          w[r] = (half_t)p;
        }
        *(f16x4*)&Pb[wave][mi][l16][(kb * 8 + quad * 2) ^ psw] = w;
      }

    // Phase 2: O^T += V^T . P^T  (V fragment read once, shared across mi)
    __builtin_amdgcn_s_setprio(1);
#pragma unroll
    for (int kc = 0; kc < 2; ++kc) {
      const f16x8 pa0 = *(const f16x8*)&Pb[wave][0][l16][(kc * 16 + quad * 4) ^ psw];
      const f16x8 pa1 = *(const f16x8*)&Pb[wave][1][l16][(kc * 16 + quad * 4) ^ psw];
#pragma unroll
      for (int nd = 0; nd < 4; ++nd) {
        const f16x8 vb = *(const f16x8*)&Vfd[(((kc * 4 + nd) * 64) + (lx ^ (kc << 2))) * 4];
        o[0][nd] = MFMA16(vb, pa0, o[0][nd]);
        o[1][nd] = MFMA16(vb, pa1, o[1][nd]);
      }
    }
    __builtin_amdgcn_s_setprio(0);

    // Rendezvous-only barrier: local LDS ops drained, but next-tile K gll and
    // V register loads stay in flight across it (no vmcnt drain).
    asm volatile("s_waitcnt lgkmcnt(0)" ::: "memory");
    __builtin_amdgcn_s_barrier();
    cur ^= 1;
  }

  // epilogue: row sum over quads, normalize, contiguous 8B stores
#pragma unroll
  for (int mi = 0; mi < 2; ++mi) {
    float rs = (lpv[mi][0] + lpv[mi][1]) + (lpv[mi][2] + lpv[mi][3]);
    rs += __shfl_xor(rs, 16);
    rs += __shfl_xor(rs, 32);
    const float inv = 1.f / rs;
    const size_t row =
        (size_t)(b * NQ + qblk * 128 + wave * 32 + mi * 16 + l16) * CC + h * HDIM;
#pragma unroll
    for (int nd = 0; nd < 4; ++nd) {
      f16x4 w;
#pragma unroll
      for (int r = 0; r < 4; ++r) w[r] = (half_t)(o[mi][nd][r] * inv);
      *(f16x4*)&x16[row + nd * 16 + quad * 4] = w;
    }
  }
}

// ---------------------------------------------------------------------------
extern "C" void kernel_launch(void* const* d_in, const int* in_sizes, int n_in,
                              void* d_out, int out_size, void* d_ws, size_t ws_size,
                              hipStream_t stream) {
  const float* query = (const float*)d_in[0];
  const float* key   = (const float*)d_in[1];
  const float* value = (const float*)d_in[2];
  const int*   qpos  = (const int*)d_in[3];
  const int*   kpos  = (const int*)d_in[4];
  const float* Wq = (const float*)d_in[5];
  const float* Wk = (const float*)d_in[6];
  const float* Wv = (const float*)d_in[7];
  const float* Wo = (const float*)d_in[8];
  const float* bo = (const float*)d_in[9];
  float* out = (float*)d_out;

  const size_t NT = (size_t)Bc * NQ * CC;  // 8.4M halfs per activation tensor
  half_t* q16 = (half_t*)d_ws;
  half_t* k16 = q16 + NT;
  half_t* v16 = k16 + NT;
  half_t* x16 = v16 + NT;        // attn output (fp16)
  half_t* W16 = x16 + NT;        // 4 weights, fp16, 1M each

  const int nbW = (CC * CC) / 8 / 256;      // 512 blocks per weight

  // weights -> fp16 (one batched launch)
  cvtW<<<dim3(nbW, 4), 256, 0, stream>>>(Wq, Wk, Wv, Wo, W16);

  const dim3 gg(CC / 128, Bc * NQ / 128);  // (8, 64)
  // fused projections: fp32 X converted in-kernel; RoPE fused for Q/K
  gemm_k<true, true, false><<<gg, 256, 0, stream>>>(
      query, W16 + 0 * (size_t)CC * CC, q16, nullptr, nullptr, qpos);
  gemm_k<true, true, false><<<gg, 256, 0, stream>>>(
      key, W16 + 1 * (size_t)CC * CC, k16, nullptr, nullptr, kpos);
  gemm_k<true, false, false><<<gg, 256, 0, stream>>>(
      value, W16 + 2 * (size_t)CC * CC, v16, nullptr, nullptr, nullptr);

  attn_kernel<<<dim3(NQ / 128, NHD, Bc), 256, 0, stream>>>(q16, k16, v16, x16);

  gemm_k<false, false, true><<<gg, 256, 0, stream>>>(
      x16, W16 + 3 * (size_t)CC * CC, nullptr, out, bo, nullptr);
}

// Round 9
// 408.434 us; speedup vs baseline: 2.4485x; 2.4485x over previous
//
#include <hip/hip_runtime.h>
#include <math.h>

typedef _Float16 half_t;
typedef __attribute__((ext_vector_type(8))) _Float16 f16x8;
typedef __attribute__((ext_vector_type(4))) _Float16 f16x4;
typedef __attribute__((ext_vector_type(4))) float f32x4;

#define MFMA16(a, b, c) __builtin_amdgcn_mfma_f32_16x16x32_f16((a), (b), (c), 0, 0, 0)

constexpr int Bc = 4, NQ = 2048, NKC = 2048, CC = 1024, NHD = 16, HDIM = 64;

__device__ __forceinline__ void async_copy16(half_t* lds, const half_t* g) {
  __builtin_amdgcn_global_load_lds(
      (const __attribute__((address_space(1))) unsigned*)g,
      (__attribute__((address_space(3))) unsigned*)lds, 16, 0, 0);
}

// ---------------------------------------------------------------------------
// fp32 -> fp16 weight converts (8 elems/thread, 4 weights batched)
// ---------------------------------------------------------------------------
__global__ __launch_bounds__(256) void cvtW(const float* __restrict__ s0,
                                            const float* __restrict__ s1,
                                            const float* __restrict__ s2,
                                            const float* __restrict__ s3,
                                            half_t* __restrict__ dst) {
  const int y = blockIdx.y;
  const float* src = (y == 0) ? s0 : (y == 1) ? s1 : (y == 2) ? s2 : s3;
  const int i = blockIdx.x * 256 + threadIdx.x;
  const f32x4 a = ((const f32x4*)src)[2 * i];
  const f32x4 b = ((const f32x4*)src)[2 * i + 1];
  f16x8 h;
#pragma unroll
  for (int j = 0; j < 4; ++j) { h[j] = (half_t)a[j]; h[4 + j] = (half_t)b[j]; }
  ((f16x8*)(dst + (size_t)y * CC * CC))[i] = h;
}

// ---------------------------------------------------------------------------
// RoPE cos/sin table build: one packed {cos,sin} fp16 dword per
// (row, halfsel, i). Same libm cosf/sinf + fp16 cast as rounds 5-8 (the
// standalone-rope regime: tiny live state, so the OCML expansion is harmless
// here). Keeping libm OUT of the MFMA GEMM epilogue is the round-8 spill fix.
// ---------------------------------------------------------------------------
__global__ __launch_bounds__(256) void ropetab(const int* __restrict__ qpos,
                                               const int* __restrict__ kpos,
                                               unsigned* __restrict__ qtab,
                                               unsigned* __restrict__ ktab) {
  const int* pos = blockIdx.y ? kpos : qpos;
  unsigned* tab  = blockIdx.y ? ktab : qtab;
  const int gid = blockIdx.x * 256 + threadIdx.x;  // (row*2 + halfsel)*16 + i
  const int i       = gid & 15;
  const int halfsel = (gid >> 4) & 1;
  const int row     = gid >> 5;
  const int p = pos[(row << 1) + halfsel];
  const float inv = __builtin_amdgcn_exp2f((float)i * -0.41524100904865773f);
  const float ang = (float)p * inv;
  union { half_t h2[2]; unsigned u; } pk;
  pk.h2[0] = (half_t)cosf(ang);
  pk.h2[1] = (half_t)sinf(ang);
  tab[gid] = pk.u;
}

// ---------------------------------------------------------------------------
// GEMM (m97 structure): out[m][n] = sum_k X[m][k]*W[n][k], MFMA fp16.
// 128x128 tile, BK=32, unpadded LDS.
//   CVT:  X is fp32; A-operand reg-staged (f32x4 loads -> cvt -> ds_write_b128,
//         prefetched across the MFMA phase). Replaces the standalone cvt16.
//   ROPE: RoPE2D fused into the fp16 epilogue via the precomputed cos/sin
//         table (coalesced dword load; fp16 math bit-identical to the
//         standalone rope kernel). No libm in this kernel.
//   FINAL: fp16 X via global_load_lds, fp32 out + bias.
// launch_bounds(256,2): grid is 512 blocks = 2 blocks/CU; 256-VGPR budget.
// ---------------------------------------------------------------------------
template <bool CVT, bool ROPE, bool FINAL>
__global__ __launch_bounds__(256, 2) void gemm_k(const void* __restrict__ Xv,
                                                 const half_t* __restrict__ W,
                                                 half_t* __restrict__ out16,
                                                 float* __restrict__ outf,
                                                 const float* __restrict__ bias,
                                                 const unsigned* __restrict__ rtab) {
  __shared__ half_t As[128 * 32];
  __shared__ half_t Bs[128 * 32];
  const int tid  = threadIdx.x;
  const int wave = tid >> 6, lane = tid & 63;
  const int quad = lane >> 4, l16 = lane & 15;
  const int m0 = blockIdx.y * 128, n0 = blockIdx.x * 128;
  const int mw = (wave >> 1) * 64, nw = (wave & 1) * 64;

  // B staging via global_load_lds (weights, fp16): instr i covers rows
  // wave*32+i*16..+16; lane: row += lane/4, k = (lane&3)*8.
  const int srow = lane >> 2, skoff = (lane & 3) * 8;
  const half_t* xb = W + (size_t)(n0 + wave * 32 + srow) * CC + skoff;
  half_t* lB0 = &Bs[(wave * 2 + 0) * 512];
  half_t* lB1 = &Bs[(wave * 2 + 1) * 512];

  // A staging (fp16 path): same gll pattern as B.
  const half_t* xa = CVT ? nullptr : (const half_t*)Xv + (size_t)(m0 + wave * 32 + srow) * CC + skoff;
  half_t* lA0 = &As[(wave * 2 + 0) * 512];
  half_t* lA1 = &As[(wave * 2 + 1) * 512];

  // A staging (fp32 CVT path): thread covers row = tid/2, halfs [akh, akh+16).
  const int arow = tid >> 1, akh = (tid & 1) * 16;
  const float* xsrc = CVT ? (const float*)Xv + (size_t)(m0 + arow) * CC + akh : nullptr;
  half_t* adst = &As[arow * 32 + akh];

  f32x4 acc[4][4] = {};
  f32x4 ar[4];
  if constexpr (CVT) {
#pragma unroll
    for (int j = 0; j < 4; ++j) ar[j] = ((const f32x4*)xsrc)[j];  // k0 = 0
  }

  for (int k0 = 0; k0 < CC; k0 += 32) {
    __syncthreads();
    if constexpr (CVT) {
      f16x8 h0, h1;
#pragma unroll
      for (int j = 0; j < 4; ++j) {
        h0[j] = (half_t)ar[0][j]; h0[4 + j] = (half_t)ar[1][j];
        h1[j] = (half_t)ar[2][j]; h1[4 + j] = (half_t)ar[3][j];
      }
      *(f16x8*)adst = h0;
      *(f16x8*)(adst + 8) = h1;
    } else {
      async_copy16(lA0, xa + k0);
      async_copy16(lA1, xa + 16 * CC + k0);
    }
    async_copy16(lB0, xb + k0);
    async_copy16(lB1, xb + 16 * CC + k0);
    __syncthreads();

    if constexpr (CVT) {
      if (k0 + 32 < CC) {
        const float* xn = xsrc + k0 + 32;
#pragma unroll
        for (int j = 0; j < 4; ++j) ar[j] = ((const f32x4*)xn)[j];
      }
    }

    f16x8 af[4], bf[4];
#pragma unroll
    for (int mi = 0; mi < 4; ++mi) af[mi] = *(const f16x8*)&As[(mw + mi * 16 + l16) * 32 + quad * 8];
#pragma unroll
    for (int ni = 0; ni < 4; ++ni) bf[ni] = *(const f16x8*)&Bs[(nw + ni * 16 + l16) * 32 + quad * 8];
#pragma unroll
    for (int mi = 0; mi < 4; ++mi)
#pragma unroll
      for (int ni = 0; ni < 4; ++ni) acc[mi][ni] = MFMA16(af[mi], bf[ni], acc[mi][ni]);
  }

  if constexpr (FINAL) {
#pragma unroll
    for (int mi = 0; mi < 4; ++mi)
#pragma unroll
      for (int ni = 0; ni < 4; ++ni)
#pragma unroll
        for (int r = 0; r < 4; ++r) {
          const size_t row = (size_t)(m0 + mw + mi * 16 + quad * 4 + r);
          const size_t col = (size_t)(n0 + nw + ni * 16 + l16);
          outf[row * CC + col] = acc[mi][ni][r] + bias[col];
        }
  } else if constexpr (ROPE) {
#pragma clang fp contract(off)
    // i = l16; pair partner at col+16 is ni odd, same thread, same r.
    // cos/sin from the precomputed table: tab[row*32 + halfsel*16 + i].
#pragma unroll
    for (int mi = 0; mi < 4; ++mi)
#pragma unroll
      for (int np = 0; np < 2; ++np) {
        const int halfsel = ((n0 + nw + np * 32) >> 5) & 1;
#pragma unroll
        for (int r = 0; r < 4; ++r) {
          const int row = m0 + mw + mi * 16 + quad * 4 + r;   // flattened b*NQ+n
          const int col1 = n0 + nw + np * 32 + l16;
          union { unsigned u; half_t h2[2]; } pk;
          pk.u = rtab[(row << 5) + (halfsel << 4) + l16];
          const half_t hc = pk.h2[0];
          const half_t hs = pk.h2[1];
          const half_t t1 = (half_t)acc[mi][2 * np + 0][r];
          const half_t t2 = (half_t)acc[mi][2 * np + 1][r];
          const half_t p1 = t1 * hc;
          const half_t p2 = t2 * hs;
          const half_t p3 = t2 * hc;
          const half_t p4 = t1 * hs;
          out16[(size_t)row * CC + col1]      = p1 - p2;
          out16[(size_t)row * CC + col1 + 16] = p3 + p4;
        }
      }
  } else {
#pragma unroll
    for (int mi = 0; mi < 4; ++mi)
#pragma unroll
      for (int ni = 0; ni < 4; ++ni)
#pragma unroll
        for (int r = 0; r < 4; ++r) {
          const size_t row = (size_t)(m0 + mw + mi * 16 + quad * 4 + r);
          const size_t col = (size_t)(n0 + nw + ni * 16 + l16);
          out16[row * CC + col] = (half_t)acc[mi][ni][r];
        }
  }
}

// ---------------------------------------------------------------------------
// Flash attention, swapped-operand, batched-phase pipeline (round-5, 110 us).
//   K: double-buffered global_load_lds, fragment-ordered via per-lane source.
//   V: reg-staged transpose pack, single swizzled buffer.
//   QK phase: K-frag pair read once per kb (shared across mi), ALL 16 MFMAs
//   issued into live st[2][4] (max ILP), THEN batched exp+pack pass and
//   8 ds_write_b64 -> one Pb settle -> ALL PV MFMA (V frags shared across
//   mi) -> rendezvous-only "s_waitcnt lgkmcnt(0)" + s_barrier (next-tile
//   loads stay in flight across it).
// LDS = 16 (Kf dbuf) + 8 (Vfd) + 16 (Pb) = 40 KB -> 4 blocks/CU.
// ---------------------------------------------------------------------------
__global__ __launch_bounds__(256, 4) void attn_kernel(const half_t* __restrict__ q16,
                                                      const half_t* __restrict__ k16,
                                                      const half_t* __restrict__ v16,
                                                      half_t* __restrict__ x16) {
  // K fragments, double-buffered: [buf][kb][kc][slot=quad*16+l16][8 halfs] (16 KB)
  __shared__ __align__(16) half_t Kf[2 * 4096];
  // V^T fragments: [kc][nd][slot'][8 halfs], slot' = quad*16 + (l16 ^ quad ^ (kc<<2)) (8 KB)
  __shared__ __align__(16) unsigned Vfd[2 * 4 * 64 * 4];
  // P key-pair dwords: [wave][mi][q=l16][m ^ ((l16&7)<<2)], m = key/2 (16 KB)
  __shared__ __align__(16) unsigned Pb[4][2][16][32];

  const int tid  = threadIdx.x;
  const int wave = tid >> 6, lane = tid & 63;
  const int quad = lane >> 4, l16 = lane & 15;
  const int lx   = lane ^ quad;  // V-read slot base (quad XORed into low bits)
  const int psw  = (l16 & 7) << 2;
  const int qblk = blockIdx.x, h = blockIdx.y, b = blockIdx.z;
  const f32x4 zero = {0.f, 0.f, 0.f, 0.f};

  // Q fragments (B-operand role): rows wave*32 + mi*16 + l16, k = kc*32 + quad*8
  f16x8 qa[2][2];
  {
    const half_t* qbase =
        q16 + (size_t)(b * NQ + qblk * 128 + wave * 32 + l16) * CC + h * HDIM + quad * 8;
#pragma unroll
    for (int mi = 0; mi < 2; ++mi)
#pragma unroll
      for (int kc = 0; kc < 2; ++kc)
        qa[mi][kc] = *(const f16x8*)(qbase + (size_t)mi * 16 * CC + kc * 32);
  }

  f32x4 o[2][4] = {};   // O^T fragments: [mi][nd], rows d = nd*16+quad*4+r, col q = l16
  f32x4 lpv[2] = {};    // per-lane partial row sums, split by r (short add chains)

  // K gll: wave w stages kb=w. Per-lane global source so linear LDS dest
  // (base + lane*16) lands in fragment order: key = w*16 + l16, d = quad*8 + kc*32.
  const half_t* kga = k16 + (size_t)(b * NKC + wave * 16 + l16) * CC + h * HDIM + quad * 8;

  // V staging: thread covers keys {2vp, 2vp+1}, d = vd0..vd0+7
  const int vp = tid & 31, vd0 = (tid >> 5) * 8;
  const half_t* vptr = v16 + (size_t)(b * NKC + 2 * vp) * CC + h * HDIM + vd0;
  const int vkc = vp >> 4, vqd = (vp & 15) >> 2, vnd = vd0 >> 4;
  const int vl16b = vd0 & 15;  // 0 or 8
  const int vswz  = vqd ^ (vkc << 2);
  const int vbase = ((vkc * 4 + vnd) * 64 + vqd * 16) * 4 + (vp & 3);

  // prologue: tile 0 in flight
  async_copy16(&Kf[(wave * 2 + 0) * 512], kga);
  async_copy16(&Kf[(wave * 2 + 1) * 512], kga + 32);
  f16x8 vr0 = *(const f16x8*)vptr;
  f16x8 vr1 = *(const f16x8*)(vptr + CC);

  int cur = 0;
  for (int kt = 0; kt < NKC; kt += 64) {
    // V transpose-pack into Vfd (this tile); rendezvous barrier of prev iter
    // guarantees all waves' reads of Vfd are complete.
#pragma unroll
    for (int i = 0; i < 8; ++i) {
      union { half_t h2[2]; unsigned u; } pk;
      pk.h2[0] = vr0[i]; pk.h2[1] = vr1[i];
      Vfd[vbase + (((vl16b + i) ^ vswz) << 2)] = pk.u;
    }
    __syncthreads();  // full drain: Kf[cur] gll (issued a tile ago) landed; Vfd visible

    if (kt + 64 < NKC) {  // issue next K tile (other buffer) + next V reg loads
      const half_t* kn = kga + (size_t)(kt + 64) * CC;
      async_copy16(&Kf[(cur ^ 1) * 4096 + (wave * 2 + 0) * 512], kn);
      async_copy16(&Kf[(cur ^ 1) * 4096 + (wave * 2 + 1) * 512], kn + 32);
      const half_t* vn = vptr + (size_t)(kt + 64) * CC;
      vr0 = *(const f16x8*)vn;
      vr1 = *(const f16x8*)(vn + CC);
    }

    const half_t* Kc = &Kf[cur * 4096];

    // Phase 1a: S^T = K.Q^T, ALL 16 MFMAs live in st[2][4] (K-frags read once per kb)
    f32x4 st[2][4];
    __builtin_amdgcn_s_setprio(1);
#pragma unroll
    for (int kb = 0; kb < 4; ++kb) {
      const f16x8 ka0 = *(const f16x8*)&Kc[((kb * 2 + 0) * 64 + lane) * 8];
      const f16x8 ka1 = *(const f16x8*)&Kc[((kb * 2 + 1) * 64 + lane) * 8];
#pragma unroll
      for (int mi = 0; mi < 2; ++mi) {
        const f32x4 t0 = MFMA16(ka0, qa[mi][0], zero);
        st[mi][kb] = MFMA16(ka1, qa[mi][1], t0);
      }
    }
    __builtin_amdgcn_s_setprio(0);

    // Phase 1b: batched exp + in-lane pack + 8 ds_write_b64
#pragma unroll
    for (int mi = 0; mi < 2; ++mi)
#pragma unroll
      for (int kb = 0; kb < 4; ++kb) {
        f16x4 w;
#pragma unroll
        for (int r = 0; r < 4; ++r) {
          const float p = __builtin_amdgcn_exp2f(st[mi][kb][r] * 0.18033688011112042f);
          lpv[mi][r] += p;
          w[r] = (half_t)p;
        }
        *(f16x4*)&Pb[wave][mi][l16][(kb * 8 + quad * 2) ^ psw] = w;
      }

    // Phase 2: O^T += V^T . P^T  (V fragment read once, shared across mi)
    __builtin_amdgcn_s_setprio(1);
#pragma unroll
    for (int kc = 0; kc < 2; ++kc) {
      const f16x8 pa0 = *(const f16x8*)&Pb[wave][0][l16][(kc * 16 + quad * 4) ^ psw];
      const f16x8 pa1 = *(const f16x8*)&Pb[wave][1][l16][(kc * 16 + quad * 4) ^ psw];
#pragma unroll
      for (int nd = 0; nd < 4; ++nd) {
        const f16x8 vb = *(const f16x8*)&Vfd[(((kc * 4 + nd) * 64) + (lx ^ (kc << 2))) * 4];
        o[0][nd] = MFMA16(vb, pa0, o[0][nd]);
        o[1][nd] = MFMA16(vb, pa1, o[1][nd]);
      }
    }
    __builtin_amdgcn_s_setprio(0);

    // Rendezvous-only barrier: local LDS ops drained, but next-tile K gll and
    // V register loads stay in flight across it (no vmcnt drain).
    asm volatile("s_waitcnt lgkmcnt(0)" ::: "memory");
    __builtin_amdgcn_s_barrier();
    cur ^= 1;
  }

  // epilogue: row sum over quads, normalize, contiguous 8B stores
#pragma unroll
  for (int mi = 0; mi < 2; ++mi) {
    float rs = (lpv[mi][0] + lpv[mi][1]) + (lpv[mi][2] + lpv[mi][3]);
    rs += __shfl_xor(rs, 16);
    rs += __shfl_xor(rs, 32);
    const float inv = 1.f / rs;
    const size_t row =
        (size_t)(b * NQ + qblk * 128 + wave * 32 + mi * 16 + l16) * CC + h * HDIM;
#pragma unroll
    for (int nd = 0; nd < 4; ++nd) {
      f16x4 w;
#pragma unroll
      for (int r = 0; r < 4; ++r) w[r] = (half_t)(o[mi][nd][r] * inv);
      *(f16x4*)&x16[row + nd * 16 + quad * 4] = w;
    }
  }
}

// ---------------------------------------------------------------------------
extern "C" void kernel_launch(void* const* d_in, const int* in_sizes, int n_in,
                              void* d_out, int out_size, void* d_ws, size_t ws_size,
                              hipStream_t stream) {
  const float* query = (const float*)d_in[0];
  const float* key   = (const float*)d_in[1];
  const float* value = (const float*)d_in[2];
  const int*   qpos  = (const int*)d_in[3];
  const int*   kpos  = (const int*)d_in[4];
  const float* Wq = (const float*)d_in[5];
  const float* Wk = (const float*)d_in[6];
  const float* Wv = (const float*)d_in[7];
  const float* Wo = (const float*)d_in[8];
  const float* bo = (const float*)d_in[9];
  float* out = (float*)d_out;

  const size_t NT = (size_t)Bc * NQ * CC;  // 8.4M halfs per activation tensor
  half_t* q16 = (half_t*)d_ws;
  half_t* k16 = q16 + NT;
  half_t* v16 = k16 + NT;
  half_t* x16 = v16 + NT;        // attn output (fp16)
  half_t* W16 = x16 + NT;        // 4 weights, fp16, 1M halfs each
  unsigned* qtab = (unsigned*)(W16 + 4 * (size_t)CC * CC);  // rope tables, 1 MB each
  unsigned* ktab = qtab + (size_t)Bc * NQ * 32;

  const int nbW = (CC * CC) / 8 / 256;      // 512 blocks per weight

  // weights -> fp16 (one batched launch); rope cos/sin tables (q and k)
  cvtW<<<dim3(nbW, 4), 256, 0, stream>>>(Wq, Wk, Wv, Wo, W16);
  ropetab<<<dim3((Bc * NQ * 32) / 256, 2), 256, 0, stream>>>(qpos, kpos, qtab, ktab);

  const dim3 gg(CC / 128, Bc * NQ / 128);  // (8, 64)
  // fused projections: fp32 X converted in-kernel; RoPE (table) fused for Q/K
  gemm_k<true, true, false><<<gg, 256, 0, stream>>>(
      query, W16 + 0 * (size_t)CC * CC, q16, nullptr, nullptr, qtab);
  gemm_k<true, true, false><<<gg, 256, 0, stream>>>(
      key, W16 + 1 * (size_t)CC * CC, k16, nullptr, nullptr, ktab);
  gemm_k<true, false, false><<<gg, 256, 0, stream>>>(
      value, W16 + 2 * (size_t)CC * CC, v16, nullptr, nullptr, nullptr);

  attn_kernel<<<dim3(NQ / 128, NHD, Bc), 256, 0, stream>>>(q16, k16, v16, x16);

  gemm_k<false, false, true><<<gg, 256, 0, stream>>>(
      x16, W16 + 3 * (size_t)CC * CC, nullptr, out, bo, nullptr);
}

// Round 11
// 379.768 us; speedup vs baseline: 2.6333x; 1.0755x over previous
//
#include <hip/hip_runtime.h>
#include <math.h>

typedef _Float16 half_t;
typedef __attribute__((ext_vector_type(8))) _Float16 f16x8;
typedef __attribute__((ext_vector_type(4))) _Float16 f16x4;
typedef __attribute__((ext_vector_type(4))) float f32x4;

#define MFMA16(a, b, c) __builtin_amdgcn_mfma_f32_16x16x32_f16((a), (b), (c), 0, 0, 0)

constexpr int Bc = 4, NQ = 2048, NKC = 2048, CC = 1024, NHD = 16, HDIM = 64;
constexpr size_t NT = (size_t)Bc * NQ * CC;

__device__ __forceinline__ void async_copy16(half_t* lds, const half_t* g) {
  __builtin_amdgcn_global_load_lds(
      (const __attribute__((address_space(1))) unsigned*)g,
      (__attribute__((address_space(3))) unsigned*)lds, 16, 0, 0);
}

// ---------------------------------------------------------------------------
// prep: y<4 -> weight fp32->fp16 convert (8 elems/thread);
//       y in {4,5} -> RoPE cos/sin table ({cos,sin} fp16 packed dword per
//       (row, halfsel, i)), 2 entries/thread. Same libm cosf/sinf + fp16 cast
//       as the standalone rope kernel (tiny live state: no spill risk here;
//       keeping libm OUT of the MFMA GEMM epilogue is the round-8 spill fix).
// ---------------------------------------------------------------------------
__global__ __launch_bounds__(256) void prep(const float* __restrict__ s0,
                                            const float* __restrict__ s1,
                                            const float* __restrict__ s2,
                                            const float* __restrict__ s3,
                                            half_t* __restrict__ wdst,
                                            const int* __restrict__ qpos,
                                            const int* __restrict__ kpos,
                                            unsigned* __restrict__ qtab,
                                            unsigned* __restrict__ ktab) {
  const int y = blockIdx.y;
  if (y < 4) {
    const float* src = (y == 0) ? s0 : (y == 1) ? s1 : (y == 2) ? s2 : s3;
    const int i = blockIdx.x * 256 + threadIdx.x;
    const f32x4 a = ((const f32x4*)src)[2 * i];
    const f32x4 b = ((const f32x4*)src)[2 * i + 1];
    f16x8 h;
#pragma unroll
    for (int j = 0; j < 4; ++j) { h[j] = (half_t)a[j]; h[4 + j] = (half_t)b[j]; }
    ((f16x8*)(wdst + (size_t)y * CC * CC))[i] = h;
  } else {
    const int* pos = (y == 5) ? kpos : qpos;
    unsigned* tab  = (y == 5) ? ktab : qtab;
#pragma unroll
    for (int rep = 0; rep < 2; ++rep) {
      const int gid = rep * (512 * 256) + blockIdx.x * 256 + threadIdx.x;
      const int i       = gid & 15;
      const int halfsel = (gid >> 4) & 1;
      const int row     = gid >> 5;
      const int p = pos[(row << 1) + halfsel];
      const float inv = __builtin_amdgcn_exp2f((float)i * -0.41524100904865773f);
      const float ang = (float)p * inv;
      union { half_t h2[2]; unsigned u; } pk;
      pk.h2[0] = (half_t)cosf(ang);
      pk.h2[1] = (half_t)sinf(ang);
      tab[gid] = pk.u;
    }
  }
}

// ---------------------------------------------------------------------------
// Merged Q/K/V projection GEMM (m97 structure), blockIdx.z picks projection.
// out[m][n] = sum_k X[m][k]*W[n][k]; 128x128 tile, BK=32, unpadded LDS.
//   A: fp32 X reg-staged (f32x4 loads -> cvt -> ds_write_b128, prefetched
//      across the MFMA phase).  B: fp16 weights via global_load_lds.
//   Epilogue: z<2 -> table-ROPE (coalesced dword cos/sin load; fp16 math
//   bit-identical to the standalone rope kernel); z==2 -> plain fp16 store.
// All branches are block-uniform and outside the K-loop (same codegen as the
// passing round-9 kernel). launch_bounds(256,2): 256-VGPR budget.
// ---------------------------------------------------------------------------
__global__ __launch_bounds__(256, 2) void gemm_qkv(const float* __restrict__ Xq,
                                                   const float* __restrict__ Xk,
                                                   const float* __restrict__ Xv,
                                                   const half_t* __restrict__ W16,
                                                   half_t* __restrict__ out_base,
                                                   const unsigned* __restrict__ qtab,
                                                   const unsigned* __restrict__ ktab) {
  __shared__ half_t As[128 * 32];
  __shared__ half_t Bs[128 * 32];
  const int tid  = threadIdx.x;
  const int wave = tid >> 6, lane = tid & 63;
  const int quad = lane >> 4, l16 = lane & 15;
  const int m0 = blockIdx.y * 128, n0 = blockIdx.x * 128;
  const int z  = blockIdx.z;
  const int mw = (wave >> 1) * 64, nw = (wave & 1) * 64;

  const float* Xf = (z == 0) ? Xq : (z == 1) ? Xk : Xv;
  const half_t* W = W16 + (size_t)z * CC * CC;
  half_t* out16   = out_base + (size_t)z * NT;
  const unsigned* rtab = (z == 0) ? qtab : ktab;

  // B staging via global_load_lds: instr i covers rows wave*32+i*16..+16;
  // lane: row += lane/4, k = (lane&3)*8.
  const int srow = lane >> 2, skoff = (lane & 3) * 8;
  const half_t* xb = W + (size_t)(n0 + wave * 32 + srow) * CC + skoff;
  half_t* lB0 = &Bs[(wave * 2 + 0) * 512];
  half_t* lB1 = &Bs[(wave * 2 + 1) * 512];

  // A staging (fp32): thread covers row = tid/2, halfs [akh, akh+16).
  const int arow = tid >> 1, akh = (tid & 1) * 16;
  const float* xsrc = Xf + (size_t)(m0 + arow) * CC + akh;
  half_t* adst = &As[arow * 32 + akh];

  f32x4 acc[4][4] = {};
  f32x4 ar[4];
#pragma unroll
  for (int j = 0; j < 4; ++j) ar[j] = ((const f32x4*)xsrc)[j];  // k0 = 0

  for (int k0 = 0; k0 < CC; k0 += 32) {
    __syncthreads();
    {
      f16x8 h0, h1;
#pragma unroll
      for (int j = 0; j < 4; ++j) {
        h0[j] = (half_t)ar[0][j]; h0[4 + j] = (half_t)ar[1][j];
        h1[j] = (half_t)ar[2][j]; h1[4 + j] = (half_t)ar[3][j];
      }
      *(f16x8*)adst = h0;
      *(f16x8*)(adst + 8) = h1;
    }
    async_copy16(lB0, xb + k0);
    async_copy16(lB1, xb + 16 * CC + k0);
    __syncthreads();

    if (k0 + 32 < CC) {
      const float* xn = xsrc + k0 + 32;
#pragma unroll
      for (int j = 0; j < 4; ++j) ar[j] = ((const f32x4*)xn)[j];
    }

    f16x8 af[4], bf[4];
#pragma unroll
    for (int mi = 0; mi < 4; ++mi) af[mi] = *(const f16x8*)&As[(mw + mi * 16 + l16) * 32 + quad * 8];
#pragma unroll
    for (int ni = 0; ni < 4; ++ni) bf[ni] = *(const f16x8*)&Bs[(nw + ni * 16 + l16) * 32 + quad * 8];
#pragma unroll
    for (int mi = 0; mi < 4; ++mi)
#pragma unroll
      for (int ni = 0; ni < 4; ++ni) acc[mi][ni] = MFMA16(af[mi], bf[ni], acc[mi][ni]);
  }

  if (z < 2) {
#pragma clang fp contract(off)
    // i = l16; pair partner at col+16 is ni odd, same thread, same r.
    // cos/sin from the precomputed table: tab[row*32 + halfsel*16 + i].
#pragma unroll
    for (int mi = 0; mi < 4; ++mi)
#pragma unroll
      for (int np = 0; np < 2; ++np) {
        const int halfsel = ((n0 + nw + np * 32) >> 5) & 1;
#pragma unroll
        for (int r = 0; r < 4; ++r) {
          const int row = m0 + mw + mi * 16 + quad * 4 + r;   // flattened b*NQ+n
          const int col1 = n0 + nw + np * 32 + l16;
          union { unsigned u; half_t h2[2]; } pk;
          pk.u = rtab[(row << 5) + (halfsel << 4) + l16];
          const half_t hc = pk.h2[0];
          const half_t hs = pk.h2[1];
          const half_t t1 = (half_t)acc[mi][2 * np + 0][r];
          const half_t t2 = (half_t)acc[mi][2 * np + 1][r];
          const half_t p1 = t1 * hc;
          const half_t p2 = t2 * hs;
          const half_t p3 = t2 * hc;
          const half_t p4 = t1 * hs;
          out16[(size_t)row * CC + col1]      = p1 - p2;
          out16[(size_t)row * CC + col1 + 16] = p3 + p4;
        }
      }
  } else {
#pragma unroll
    for (int mi = 0; mi < 4; ++mi)
#pragma unroll
      for (int ni = 0; ni < 4; ++ni)
#pragma unroll
        for (int r = 0; r < 4; ++r) {
          const size_t row = (size_t)(m0 + mw + mi * 16 + quad * 4 + r);
          const size_t col = (size_t)(n0 + nw + ni * 16 + l16);
          out16[row * CC + col] = (half_t)acc[mi][ni][r];
        }
  }
}

// ---------------------------------------------------------------------------
// Final GEMM (m97 structure): fp16 X via global_load_lds, fp32 out + bias.
// ---------------------------------------------------------------------------
__global__ __launch_bounds__(256, 2) void gemm_fin(const half_t* __restrict__ X,
                                                   const half_t* __restrict__ W,
                                                   float* __restrict__ outf,
                                                   const float* __restrict__ bias) {
  __shared__ half_t As[128 * 32];
  __shared__ half_t Bs[128 * 32];
  const int tid  = threadIdx.x;
  const int wave = tid >> 6, lane = tid & 63;
  const int quad = lane >> 4, l16 = lane & 15;
  const int m0 = blockIdx.y * 128, n0 = blockIdx.x * 128;
  const int mw = (wave >> 1) * 64, nw = (wave & 1) * 64;

  const int srow = lane >> 2, skoff = (lane & 3) * 8;
  const half_t* xa = X + (size_t)(m0 + wave * 32 + srow) * CC + skoff;
  const half_t* xb = W + (size_t)(n0 + wave * 32 + srow) * CC + skoff;
  half_t* lA0 = &As[(wave * 2 + 0) * 512];
  half_t* lA1 = &As[(wave * 2 + 1) * 512];
  half_t* lB0 = &Bs[(wave * 2 + 0) * 512];
  half_t* lB1 = &Bs[(wave * 2 + 1) * 512];

  f32x4 acc[4][4] = {};

  for (int k0 = 0; k0 < CC; k0 += 32) {
    __syncthreads();
    async_copy16(lA0, xa + k0);
    async_copy16(lA1, xa + 16 * CC + k0);
    async_copy16(lB0, xb + k0);
    async_copy16(lB1, xb + 16 * CC + k0);
    __syncthreads();

    f16x8 af[4], bf[4];
#pragma unroll
    for (int mi = 0; mi < 4; ++mi) af[mi] = *(const f16x8*)&As[(mw + mi * 16 + l16) * 32 + quad * 8];
#pragma unroll
    for (int ni = 0; ni < 4; ++ni) bf[ni] = *(const f16x8*)&Bs[(nw + ni * 16 + l16) * 32 + quad * 8];
#pragma unroll
    for (int mi = 0; mi < 4; ++mi)
#pragma unroll
      for (int ni = 0; ni < 4; ++ni) acc[mi][ni] = MFMA16(af[mi], bf[ni], acc[mi][ni]);
  }

#pragma unroll
  for (int mi = 0; mi < 4; ++mi)
#pragma unroll
    for (int ni = 0; ni < 4; ++ni)
#pragma unroll
      for (int r = 0; r < 4; ++r) {
        const size_t row = (size_t)(m0 + mw + mi * 16 + quad * 4 + r);
        const size_t col = (size_t)(n0 + nw + ni * 16 + l16);
        outf[row * CC + col] = acc[mi][ni][r] + bias[col];
      }
}

// ---------------------------------------------------------------------------
// Flash attention, swapped-operand, batched-phase pipeline (round-5, 110 us).
//   K: double-buffered global_load_lds, fragment-ordered via per-lane source.
//   V: reg-staged transpose pack, single swizzled buffer.
//   QK phase: K-frag pair read once per kb (shared across mi), ALL 16 MFMAs
//   issued into live st[2][4] (max ILP), THEN batched exp+pack pass and
//   8 ds_write_b64 -> one Pb settle -> ALL PV MFMA (V frags shared across
//   mi) -> rendezvous-only "s_waitcnt lgkmcnt(0)" + s_barrier (next-tile
//   loads stay in flight across it).
// LDS = 16 (Kf dbuf) + 8 (Vfd) + 16 (Pb) = 40 KB -> 4 blocks/CU.
// ---------------------------------------------------------------------------
__global__ __launch_bounds__(256, 4) void attn_kernel(const half_t* __restrict__ q16,
                                                      const half_t* __restrict__ k16,
                                                      const half_t* __restrict__ v16,
                                                      half_t* __restrict__ x16) {
  // K fragments, double-buffered: [buf][kb][kc][slot=quad*16+l16][8 halfs] (16 KB)
  __shared__ __align__(16) half_t Kf[2 * 4096];
  // V^T fragments: [kc][nd][slot'][8 halfs], slot' = quad*16 + (l16 ^ quad ^ (kc<<2)) (8 KB)
  __shared__ __align__(16) unsigned Vfd[2 * 4 * 64 * 4];
  // P key-pair dwords: [wave][mi][q=l16][m ^ ((l16&7)<<2)], m = key/2 (16 KB)
  __shared__ __align__(16) unsigned Pb[4][2][16][32];

  const int tid  = threadIdx.x;
  const int wave = tid >> 6, lane = tid & 63;
  const int quad = lane >> 4, l16 = lane & 15;
  const int lx   = lane ^ quad;  // V-read slot base (quad XORed into low bits)
  const int psw  = (l16 & 7) << 2;
  const int qblk = blockIdx.x, h = blockIdx.y, b = blockIdx.z;
  const f32x4 zero = {0.f, 0.f, 0.f, 0.f};

  // Q fragments (B-operand role): rows wave*32 + mi*16 + l16, k = kc*32 + quad*8
  f16x8 qa[2][2];
  {
    const half_t* qbase =
        q16 + (size_t)(b * NQ + qblk * 128 + wave * 32 + l16) * CC + h * HDIM + quad * 8;
#pragma unroll
    for (int mi = 0; mi < 2; ++mi)
#pragma unroll
      for (int kc = 0; kc < 2; ++kc)
        qa[mi][kc] = *(const f16x8*)(qbase + (size_t)mi * 16 * CC + kc * 32);
  }

  f32x4 o[2][4] = {};   // O^T fragments: [mi][nd], rows d = nd*16+quad*4+r, col q = l16
  f32x4 lpv[2] = {};    // per-lane partial row sums, split by r (short add chains)

  // K gll: wave w stages kb=w. Per-lane global source so linear LDS dest
  // (base + lane*16) lands in fragment order: key = w*16 + l16, d = quad*8 + kc*32.
  const half_t* kga = k16 + (size_t)(b * NKC + wave * 16 + l16) * CC + h * HDIM + quad * 8;

  // V staging: thread covers keys {2vp, 2vp+1}, d = vd0..vd0+7
  const int vp = tid & 31, vd0 = (tid >> 5) * 8;
  const half_t* vptr = v16 + (size_t)(b * NKC + 2 * vp) * CC + h * HDIM + vd0;
  const int vkc = vp >> 4, vqd = (vp & 15) >> 2, vnd = vd0 >> 4;
  const int vl16b = vd0 & 15;  // 0 or 8
  const int vswz  = vqd ^ (vkc << 2);
  const int vbase = ((vkc * 4 + vnd) * 64 + vqd * 16) * 4 + (vp & 3);

  // prologue: tile 0 in flight
  async_copy16(&Kf[(wave * 2 + 0) * 512], kga);
  async_copy16(&Kf[(wave * 2 + 1) * 512], kga + 32);
  f16x8 vr0 = *(const f16x8*)vptr;
  f16x8 vr1 = *(const f16x8*)(vptr + CC);

  int cur = 0;
  for (int kt = 0; kt < NKC; kt += 64) {
    // V transpose-pack into Vfd (this tile); rendezvous barrier of prev iter
    // guarantees all waves' reads of Vfd are complete.
#pragma unroll
    for (int i = 0; i < 8; ++i) {
      union { half_t h2[2]; unsigned u; } pk;
      pk.h2[0] = vr0[i]; pk.h2[1] = vr1[i];
      Vfd[vbase + (((vl16b + i) ^ vswz) << 2)] = pk.u;
    }
    __syncthreads();  // full drain: Kf[cur] gll (issued a tile ago) landed; Vfd visible

    if (kt + 64 < NKC) {  // issue next K tile (other buffer) + next V reg loads
      const half_t* kn = kga + (size_t)(kt + 64) * CC;
      async_copy16(&Kf[(cur ^ 1) * 4096 + (wave * 2 + 0) * 512], kn);
      async_copy16(&Kf[(cur ^ 1) * 4096 + (wave * 2 + 1) * 512], kn + 32);
      const half_t* vn = vptr + (size_t)(kt + 64) * CC;
      vr0 = *(const f16x8*)vn;
      vr1 = *(const f16x8*)(vn + CC);
    }

    const half_t* Kc = &Kf[cur * 4096];

    // Phase 1a: S^T = K.Q^T, ALL 16 MFMAs live in st[2][4] (K-frags read once per kb)
    f32x4 st[2][4];
    __builtin_amdgcn_s_setprio(1);
#pragma unroll
    for (int kb = 0; kb < 4; ++kb) {
      const f16x8 ka0 = *(const f16x8*)&Kc[((kb * 2 + 0) * 64 + lane) * 8];
      const f16x8 ka1 = *(const f16x8*)&Kc[((kb * 2 + 1) * 64 + lane) * 8];
#pragma unroll
      for (int mi = 0; mi < 2; ++mi) {
        const f32x4 t0 = MFMA16(ka0, qa[mi][0], zero);
        st[mi][kb] = MFMA16(ka1, qa[mi][1], t0);
      }
    }
    __builtin_amdgcn_s_setprio(0);

    // Phase 1b: batched exp + in-lane pack + 8 ds_write_b64
#pragma unroll
    for (int mi = 0; mi < 2; ++mi)
#pragma unroll
      for (int kb = 0; kb < 4; ++kb) {
        f16x4 w;
#pragma unroll
        for (int r = 0; r < 4; ++r) {
          const float p = __builtin_amdgcn_exp2f(st[mi][kb][r] * 0.18033688011112042f);
          lpv[mi][r] += p;
          w[r] = (half_t)p;
        }
        *(f16x4*)&Pb[wave][mi][l16][(kb * 8 + quad * 2) ^ psw] = w;
      }

    // Phase 2: O^T += V^T . P^T  (V fragment read once, shared across mi)
    __builtin_amdgcn_s_setprio(1);
#pragma unroll
    for (int kc = 0; kc < 2; ++kc) {
      const f16x8 pa0 = *(const f16x8*)&Pb[wave][0][l16][(kc * 16 + quad * 4) ^ psw];
      const f16x8 pa1 = *(const f16x8*)&Pb[wave][1][l16][(kc * 16 + quad * 4) ^ psw];
#pragma unroll
      for (int nd = 0; nd < 4; ++nd) {
        const f16x8 vb = *(const f16x8*)&Vfd[(((kc * 4 + nd) * 64) + (lx ^ (kc << 2))) * 4];
        o[0][nd] = MFMA16(vb, pa0, o[0][nd]);
        o[1][nd] = MFMA16(vb, pa1, o[1][nd]);
      }
    }
    __builtin_amdgcn_s_setprio(0);

    // Rendezvous-only barrier: local LDS ops drained, but next-tile K gll and
    // V register loads stay in flight across it (no vmcnt drain).
    asm volatile("s_waitcnt lgkmcnt(0)" ::: "memory");
    __builtin_amdgcn_s_barrier();
    cur ^= 1;
  }

  // epilogue: row sum over quads, normalize, contiguous 8B stores
#pragma unroll
  for (int mi = 0; mi < 2; ++mi) {
    float rs = (lpv[mi][0] + lpv[mi][1]) + (lpv[mi][2] + lpv[mi][3]);
    rs += __shfl_xor(rs, 16);
    rs += __shfl_xor(rs, 32);
    const float inv = 1.f / rs;
    const size_t row =
        (size_t)(b * NQ + qblk * 128 + wave * 32 + mi * 16 + l16) * CC + h * HDIM;
#pragma unroll
    for (int nd = 0; nd < 4; ++nd) {
      f16x4 w;
#pragma unroll
      for (int r = 0; r < 4; ++r) w[r] = (half_t)(o[mi][nd][r] * inv);
      *(f16x4*)&x16[row + nd * 16 + quad * 4] = w;
    }
  }
}

// ---------------------------------------------------------------------------
extern "C" void kernel_launch(void* const* d_in, const int* in_sizes, int n_in,
                              void* d_out, int out_size, void* d_ws, size_t ws_size,
                              hipStream_t stream) {
  const float* query = (const float*)d_in[0];
  const float* key   = (const float*)d_in[1];
  const float* value = (const float*)d_in[2];
  const int*   qpos  = (const int*)d_in[3];
  const int*   kpos  = (const int*)d_in[4];
  const float* Wq = (const float*)d_in[5];
  const float* Wk = (const float*)d_in[6];
  const float* Wv = (const float*)d_in[7];
  const float* Wo = (const float*)d_in[8];
  const float* bo = (const float*)d_in[9];
  float* out = (float*)d_out;

  half_t* q16 = (half_t*)d_ws;
  half_t* k16 = q16 + NT;
  half_t* v16 = k16 + NT;
  half_t* x16 = v16 + NT;        // attn output (fp16)
  half_t* W16 = x16 + NT;        // 4 weights, fp16, 1M halfs each
  unsigned* qtab = (unsigned*)(W16 + 4 * (size_t)CC * CC);  // rope tables, 1 MB each
  unsigned* ktab = qtab + (size_t)Bc * NQ * 32;

  // weights -> fp16 + rope cos/sin tables, one launch
  prep<<<dim3(512, 6), 256, 0, stream>>>(Wq, Wk, Wv, Wo, W16, qpos, kpos, qtab, ktab);

  // merged Q/K/V projections (CVT + table-ROPE fused), one launch
  gemm_qkv<<<dim3(CC / 128, Bc * NQ / 128, 3), 256, 0, stream>>>(
      query, key, value, W16, q16, qtab, ktab);

  attn_kernel<<<dim3(NQ / 128, NHD, Bc), 256, 0, stream>>>(q16, k16, v16, x16);

  gemm_fin<<<dim3(CC / 128, Bc * NQ / 128), 256, 0, stream>>>(
      x16, W16 + 3 * (size_t)CC * CC, out, bo);
}